// Round 4
// baseline (1104.014 us; speedup 1.0000x reference)
//
#include <hip/hip_runtime.h>

#define N_NODES 100000
#define N_EDGES 1600000
#define IN_F 128
#define OUT_F 64
#define LN_EPS 1e-5f

#define BUCKET_SHIFT 7                       // 128 nodes per bucket
#define NB ((N_NODES + 127) >> BUCKET_SHIFT) // 782

#define PART_BLOCKS 128
#define PART_THREADS 1024
#define PART_CHUNK ((N_EDGES + PART_BLOCKS - 1) / PART_BLOCKS)  // 12500

#define ACC_T 512

__device__ __forceinline__ unsigned short f2bf(float f) {
  unsigned int u = __float_as_uint(f);
  unsigned int r = (u + 0x7FFFu + ((u >> 16) & 1u)) >> 16;
  return (unsigned short)r;
}
__device__ __forceinline__ float bf2f(unsigned short h) {
  return __uint_as_float((unsigned int)h << 16);
}

// ---------------------------------------------------------------------------
// Kernel 1: dual GEMM (unchanged from R3 — passed).
//   blocks [0,512):    support = x @ W               -> bf16 [N,64]
//   blocks [512,1024): resid   = x @ res_w.T + res_b -> f32  [N,64]
// ---------------------------------------------------------------------------
__global__ __launch_bounds__(256) void dual_gemm(
    const float* __restrict__ x, const float* __restrict__ W,
    const float* __restrict__ res_w, const float* __restrict__ res_b,
    unsigned short* __restrict__ support, float* __restrict__ resid) {
  __shared__ float xl[4 * IN_F];
  const int o = threadIdx.x & 63;
  const int wid = threadIdx.x >> 6;
  const int half = 512;
  const bool do_resid = blockIdx.x >= half;
  const int b0 = do_resid ? (int)blockIdx.x - half : (int)blockIdx.x;

  float wc[IN_F];
  if (do_resid) {
    const float4* rwrow = (const float4*)(res_w + (size_t)o * IN_F);
#pragma unroll
    for (int k4 = 0; k4 < IN_F / 4; ++k4) {
      float4 t = rwrow[k4];
      wc[k4 * 4 + 0] = t.x; wc[k4 * 4 + 1] = t.y;
      wc[k4 * 4 + 2] = t.z; wc[k4 * 4 + 3] = t.w;
    }
  } else {
#pragma unroll
    for (int k = 0; k < IN_F; ++k) wc[k] = W[k * OUT_F + o];
  }
  const float rb = do_resid ? res_b[o] : 0.f;

  const int ngroups = N_NODES / 4;  // 25000 exact
  for (int g = b0; g < ngroups; g += half) {
    __syncthreads();
    if (threadIdx.x < 128) {
      ((float4*)xl)[threadIdx.x] =
          ((const float4*)(x + (size_t)g * 4 * IN_F))[threadIdx.x];
    }
    __syncthreads();

    const float4* xr = (const float4*)(xl + wid * IN_F);
    float acc = 0.f;
#pragma unroll
    for (int k4 = 0; k4 < IN_F / 4; ++k4) {
      float4 xv = xr[k4];
      acc = fmaf(xv.x, wc[k4 * 4 + 0], acc);
      acc = fmaf(xv.y, wc[k4 * 4 + 1], acc);
      acc = fmaf(xv.z, wc[k4 * 4 + 2], acc);
      acc = fmaf(xv.w, wc[k4 * 4 + 3], acc);
    }
    const size_t idx = ((size_t)g * 4 + wid) * OUT_F + o;
    if (do_resid) resid[idx] = acc + rb;
    else          support[idx] = f2bf(acc);
  }
}

// ---------------------------------------------------------------------------
// Kernel 2: bucket histogram (LDS-aggregated).
// ---------------------------------------------------------------------------
__global__ __launch_bounds__(256) void bucket_hist(const int* __restrict__ edst,
                                                   int* __restrict__ bcnt) {
  __shared__ int lc[NB];
  for (int i = threadIdx.x; i < NB; i += 256) lc[i] = 0;
  __syncthreads();
  const int stride = gridDim.x * 256;
  for (int i = blockIdx.x * 256 + threadIdx.x; i < N_EDGES; i += stride)
    atomicAdd(&lc[edst[i] >> BUCKET_SHIFT], 1);
  __syncthreads();
  for (int i = threadIdx.x; i < NB; i += 256)
    if (lc[i]) atomicAdd(&bcnt[i], lc[i]);
}

// ---------------------------------------------------------------------------
// Kernel 3: exclusive scan over NB bucket counts (single block).
// ---------------------------------------------------------------------------
__global__ __launch_bounds__(1024) void bucket_scan(
    const int* __restrict__ bcnt, int* __restrict__ gcur,
    int* __restrict__ bstart) {
  __shared__ int sh[1024];
  const int t = threadIdx.x;
  const int v = (t < NB) ? bcnt[t] : 0;
  sh[t] = v;
  __syncthreads();
  for (int off = 1; off < 1024; off <<= 1) {
    int tm = (t >= off) ? sh[t - off] : 0;
    __syncthreads();
    sh[t] += tm;
    __syncthreads();
  }
  if (t < NB) {
    const int ex = sh[t] - v;
    gcur[t] = ex;
    bstart[t] = ex;
  }
  if (t == 0) bstart[NB] = N_EDGES;
}

// ---------------------------------------------------------------------------
// Kernel 4: block-aggregated partition into bucket-contiguous runs.
// Packed 8B records: .x = (src<<7) | (dst&127)   (src < 2^17), .y = w bits.
// 128 blocks -> ~12500 edges/block -> ~16-edge (128B) runs per bucket.
// ---------------------------------------------------------------------------
__global__ __launch_bounds__(PART_THREADS) void partition(
    const int* __restrict__ esrc, const int* __restrict__ edst,
    const float* __restrict__ ew, int* __restrict__ gcur,
    int2* __restrict__ part) {
  __shared__ int lcnt[NB];
  __shared__ int lpos[NB];
  const int t = threadIdx.x;
  for (int i = t; i < NB; i += PART_THREADS) lcnt[i] = 0;
  __syncthreads();
  const int beg = blockIdx.x * PART_CHUNK;
  const int end = min(beg + PART_CHUNK, N_EDGES);
  for (int i = beg + t; i < end; i += PART_THREADS)
    atomicAdd(&lcnt[edst[i] >> BUCKET_SHIFT], 1);
  __syncthreads();
  for (int i = t; i < NB; i += PART_THREADS)
    lpos[i] = lcnt[i] ? atomicAdd(&gcur[i], lcnt[i]) : 0;
  __syncthreads();
  for (int i = beg + t; i < end; i += PART_THREADS) {
    const int d = edst[i];
    const int p = atomicAdd(&lpos[d >> BUCKET_SHIFT], 1);
    part[p] = make_int2((esrc[i] << BUCKET_SHIFT) | (d & 127),
                        __float_as_int(ew[i]));
  }
}

// ---------------------------------------------------------------------------
// Kernel 5: fused bucket accumulate + finalize. One block per bucket.
// Edge metadata staged cooperatively into LDS (coalesced), then each wave
// processes a 64-edge slice with an 8-deep unrolled gather pipeline (MLP=8),
// accumulating into the 32KB LDS tile via ds_add. Epilogue: bias + LN(64)
// + ReLU + resid, one coalesced store per node.
// ---------------------------------------------------------------------------
__global__ __launch_bounds__(ACC_T, 4) void bucket_accum(
    const unsigned short* __restrict__ support, const int2* __restrict__ part,
    const int* __restrict__ bstart, const float* __restrict__ resid,
    const float* __restrict__ bias, const float* __restrict__ gamma,
    const float* __restrict__ beta, float* __restrict__ out) {
  __shared__ float acc[128 * OUT_F];  // 32 KB
  __shared__ int2 stage[ACC_T];       // 4 KB
  const int o = threadIdx.x & 63;
  const int wid = threadIdx.x >> 6;  // 0..7
  const int b = blockIdx.x;

  for (int i = threadIdx.x; i < 128 * OUT_F; i += ACC_T) acc[i] = 0.f;

  const int beg = bstart[b];
  const int end = bstart[b + 1];

  for (int base = beg; base < end; base += ACC_T) {
    const int n = min(ACC_T, end - base);
    __syncthreads();  // stage reuse + (first iter) acc zero-init
    if (threadIdx.x < n) stage[threadIdx.x] = part[base + threadIdx.x];
    __syncthreads();

    const int s0 = wid * 64;
    const int cw = min(64, n - s0);  // may be <= 0 for tail chunks
    int i = 0;
    for (; i + 8 <= cw; i += 8) {
      int2 e0 = stage[s0 + i + 0];
      int2 e1 = stage[s0 + i + 1];
      int2 e2 = stage[s0 + i + 2];
      int2 e3 = stage[s0 + i + 3];
      int2 e4 = stage[s0 + i + 4];
      int2 e5 = stage[s0 + i + 5];
      int2 e6 = stage[s0 + i + 6];
      int2 e7 = stage[s0 + i + 7];
      float v0 = bf2f(support[((size_t)((unsigned)e0.x >> 7) << 6) + o]);
      float v1 = bf2f(support[((size_t)((unsigned)e1.x >> 7) << 6) + o]);
      float v2 = bf2f(support[((size_t)((unsigned)e2.x >> 7) << 6) + o]);
      float v3 = bf2f(support[((size_t)((unsigned)e3.x >> 7) << 6) + o]);
      float v4 = bf2f(support[((size_t)((unsigned)e4.x >> 7) << 6) + o]);
      float v5 = bf2f(support[((size_t)((unsigned)e5.x >> 7) << 6) + o]);
      float v6 = bf2f(support[((size_t)((unsigned)e6.x >> 7) << 6) + o]);
      float v7 = bf2f(support[((size_t)((unsigned)e7.x >> 7) << 6) + o]);
      atomicAdd(&acc[((e0.x & 127) << 6) + o], v0 * __int_as_float(e0.y));
      atomicAdd(&acc[((e1.x & 127) << 6) + o], v1 * __int_as_float(e1.y));
      atomicAdd(&acc[((e2.x & 127) << 6) + o], v2 * __int_as_float(e2.y));
      atomicAdd(&acc[((e3.x & 127) << 6) + o], v3 * __int_as_float(e3.y));
      atomicAdd(&acc[((e4.x & 127) << 6) + o], v4 * __int_as_float(e4.y));
      atomicAdd(&acc[((e5.x & 127) << 6) + o], v5 * __int_as_float(e5.y));
      atomicAdd(&acc[((e6.x & 127) << 6) + o], v6 * __int_as_float(e6.y));
      atomicAdd(&acc[((e7.x & 127) << 6) + o], v7 * __int_as_float(e7.y));
    }
    for (; i < cw; ++i) {
      int2 e = stage[s0 + i];
      float v = bf2f(support[((size_t)((unsigned)e.x >> 7) << 6) + o]);
      atomicAdd(&acc[((e.x & 127) << 6) + o], v * __int_as_float(e.y));
    }
  }
  __syncthreads();

  const float bi = bias[o];
  const float ga = gamma[o];
  const float be = beta[o];
  for (int j = wid; j < 128; j += 8) {
    const int n = (b << BUCKET_SHIFT) + j;
    if (n >= N_NODES) break;
    const float v = acc[(j << 6) + o] + bi;
    float s = v, sq = v * v;
#pragma unroll
    for (int off = 32; off > 0; off >>= 1) {
      s += __shfl_xor(s, off, 64);
      sq += __shfl_xor(sq, off, 64);
    }
    const float mu = s * (1.f / 64.f);
    const float var = sq * (1.f / 64.f) - mu * mu;
    const float r = rsqrtf(var + LN_EPS);
    const float nrm = fmaxf((v - mu) * r * ga + be, 0.f);
    out[(size_t)n * OUT_F + o] = nrm + resid[(size_t)n * OUT_F + o];
  }
}

// ---------------------------------------------------------------------------
extern "C" void kernel_launch(void* const* d_in, const int* in_sizes, int n_in,
                              void* d_out, int out_size, void* d_ws,
                              size_t ws_size, hipStream_t stream) {
  const float* x      = (const float*)d_in[0];
  const float* weight = (const float*)d_in[1];
  const float* bias   = (const float*)d_in[2];
  const float* gamma  = (const float*)d_in[3];
  const float* beta   = (const float*)d_in[4];
  const float* res_w  = (const float*)d_in[5];
  const float* res_b  = (const float*)d_in[6];
  const float* ew     = (const float*)d_in[7];
  const int*   esrc   = (const int*)d_in[8];
  const int*   edst   = (const int*)d_in[9];
  float* out = (float*)d_out;

  char* ws = (char*)d_ws;
  size_t off = 0;
  auto alloc = [&](size_t bytes) {
    void* p = ws + off;
    off += (bytes + 255) & ~(size_t)255;
    return p;
  };
  unsigned short* support = (unsigned short*)alloc((size_t)N_NODES * OUT_F * 2); // 12.8MB
  float* resid   = (float*)alloc((size_t)N_NODES * OUT_F * sizeof(float));       // 25.6MB
  int2*  part    = (int2*)alloc((size_t)N_EDGES * sizeof(int2));                 // 12.8MB
  int*   bcnt    = (int*)alloc((size_t)NB * sizeof(int));
  int*   gcur    = (int*)alloc((size_t)NB * sizeof(int));
  int*   bstart  = (int*)alloc((size_t)(NB + 1) * sizeof(int));

  hipMemsetAsync(bcnt, 0, (size_t)NB * sizeof(int), stream);

  dual_gemm<<<1024, 256, 0, stream>>>(x, weight, res_w, res_b, support, resid);
  bucket_hist<<<512, 256, 0, stream>>>(edst, bcnt);
  bucket_scan<<<1, 1024, 0, stream>>>(bcnt, gcur, bstart);
  partition<<<PART_BLOCKS, PART_THREADS, 0, stream>>>(esrc, edst, ew, gcur, part);
  bucket_accum<<<NB, ACC_T, 0, stream>>>(support, part, bstart, resid,
                                         bias, gamma, beta, out);
}

// Round 5
// 380.611 us; speedup vs baseline: 2.9006x; 2.9006x over previous
//
#include <hip/hip_runtime.h>

#define N_NODES 100000
#define N_EDGES 1600000
#define IN_F 128
#define OUT_F 64
#define LN_EPS 1e-5f

#define BSHIFT 6                              // 64 nodes per bucket
#define BNODES 64
#define NB ((N_NODES + BNODES - 1) >> BSHIFT) // 1563

#define PART_BLOCKS 64
#define PART_THREADS 1024
#define PART_CHUNK ((N_EDGES + PART_BLOCKS - 1) / PART_BLOCKS)  // 25000

#define CH 2048  // per-chunk sort capacity (chunking => no capacity assumption)

__device__ __forceinline__ unsigned short f2bf(float f) {
  unsigned int u = __float_as_uint(f);
  unsigned int r = (u + 0x7FFFu + ((u >> 16) & 1u)) >> 16;
  return (unsigned short)r;
}
__device__ __forceinline__ float bf2f(unsigned short h) {
  return __uint_as_float((unsigned int)h << 16);
}

// ---------------------------------------------------------------------------
// Kernel 1: dual GEMM, x staged ONCE for both outputs.
// 8 waves/block: waves 0-3 -> support = x@W (bf16), waves 4-7 -> resid =
// x@res_w.T + res_b (f32). Each wave computes 2 of the 8 staged rows.
// ---------------------------------------------------------------------------
__global__ __launch_bounds__(512) void dual_gemm(
    const float* __restrict__ x, const float* __restrict__ W,
    const float* __restrict__ res_w, const float* __restrict__ res_b,
    unsigned short* __restrict__ support, float* __restrict__ resid) {
  __shared__ float xl[8 * IN_F];  // 4 KB
  const int o = threadIdx.x & 63;
  const int wid = threadIdx.x >> 6;  // 0..7
  const bool do_res = wid >= 4;

  float wc[IN_F];
  if (do_res) {
    const float4* rwrow = (const float4*)(res_w + (size_t)o * IN_F);
#pragma unroll
    for (int k4 = 0; k4 < IN_F / 4; ++k4) {
      float4 t = rwrow[k4];
      wc[k4 * 4 + 0] = t.x; wc[k4 * 4 + 1] = t.y;
      wc[k4 * 4 + 2] = t.z; wc[k4 * 4 + 3] = t.w;
    }
  } else {
#pragma unroll
    for (int k = 0; k < IN_F; ++k) wc[k] = W[k * OUT_F + o];
  }
  const float rb = res_b[o];

  const int ngroups = N_NODES / 8;  // 12500 exact
  for (int g = blockIdx.x; g < ngroups; g += gridDim.x) {
    __syncthreads();
    if (threadIdx.x < 256) {
      ((float4*)xl)[threadIdx.x] =
          ((const float4*)(x + (size_t)g * 8 * IN_F))[threadIdx.x];
    }
    __syncthreads();

    const int r0 = (wid & 3) * 2;
    const float4* xr0 = (const float4*)(xl + r0 * IN_F);
    const float4* xr1 = (const float4*)(xl + (r0 + 1) * IN_F);
    float a0 = 0.f, a1 = 0.f;
#pragma unroll
    for (int k4 = 0; k4 < IN_F / 4; ++k4) {
      float4 u = xr0[k4];
      float4 v = xr1[k4];
      a0 = fmaf(u.x, wc[k4 * 4 + 0], a0);
      a1 = fmaf(v.x, wc[k4 * 4 + 0], a1);
      a0 = fmaf(u.y, wc[k4 * 4 + 1], a0);
      a1 = fmaf(v.y, wc[k4 * 4 + 1], a1);
      a0 = fmaf(u.z, wc[k4 * 4 + 2], a0);
      a1 = fmaf(v.z, wc[k4 * 4 + 2], a1);
      a0 = fmaf(u.w, wc[k4 * 4 + 3], a0);
      a1 = fmaf(v.w, wc[k4 * 4 + 3], a1);
    }
    const size_t i0 = ((size_t)g * 8 + r0) * OUT_F + o;
    if (do_res) {
      resid[i0] = a0 + rb;
      resid[i0 + OUT_F] = a1 + rb;
    } else {
      support[i0] = f2bf(a0);
      support[i0 + OUT_F] = f2bf(a1);
    }
  }
}

// ---------------------------------------------------------------------------
// Kernel 2: bucket histogram (LDS-aggregated, int atomics).
// ---------------------------------------------------------------------------
__global__ __launch_bounds__(256) void bucket_hist(const int* __restrict__ edst,
                                                   int* __restrict__ bcnt) {
  __shared__ int lc[NB];
  for (int i = threadIdx.x; i < NB; i += 256) lc[i] = 0;
  __syncthreads();
  const int stride = gridDim.x * 256;
  for (int i = blockIdx.x * 256 + threadIdx.x; i < N_EDGES; i += stride)
    atomicAdd(&lc[edst[i] >> BSHIFT], 1);
  __syncthreads();
  for (int i = threadIdx.x; i < NB; i += 256)
    if (lc[i]) atomicAdd(&bcnt[i], lc[i]);
}

// ---------------------------------------------------------------------------
// Kernel 3: exclusive scan over NB=1563 bucket counts (one 1024-thread block,
// two passes of a 1024-wide doubling scan).
// ---------------------------------------------------------------------------
__global__ __launch_bounds__(1024) void bucket_scan(
    const int* __restrict__ bcnt, int* __restrict__ gcur,
    int* __restrict__ bstart) {
  __shared__ int sh[1024];
  __shared__ int tot;
  const int t = threadIdx.x;

  // half 1: [0, 1024)  (all indices < NB)
  int v = bcnt[t];
  sh[t] = v;
  __syncthreads();
  for (int off = 1; off < 1024; off <<= 1) {
    int u = (t >= off) ? sh[t - off] : 0;
    __syncthreads();
    sh[t] += u;
    __syncthreads();
  }
  const int e1 = sh[t] - v;
  gcur[t] = e1;
  bstart[t] = e1;
  if (t == 1023) tot = sh[1023];
  __syncthreads();

  // half 2: [1024, 2048)
  const int t2 = 1024 + t;
  int v2 = (t2 < NB) ? bcnt[t2] : 0;
  sh[t] = v2;
  __syncthreads();
  for (int off = 1; off < 1024; off <<= 1) {
    int u = (t >= off) ? sh[t - off] : 0;
    __syncthreads();
    sh[t] += u;
    __syncthreads();
  }
  if (t2 < NB) {
    const int e2 = sh[t] - v2 + tot;
    gcur[t2] = e2;
    bstart[t2] = e2;
  }
  if (t == 0) bstart[NB] = N_EDGES;
}

// ---------------------------------------------------------------------------
// Kernel 4: block-aggregated partition into bucket-contiguous runs.
// Packed 8B records: .x = (src<<6) | (dst&63)  (src < 2^17 -> 23 bits), .y = w.
// 64 blocks -> 25000 edges/block -> ~16-record (128B) runs per bucket.
// ---------------------------------------------------------------------------
__global__ __launch_bounds__(PART_THREADS) void partition(
    const int* __restrict__ esrc, const int* __restrict__ edst,
    const float* __restrict__ ew, int* __restrict__ gcur,
    int2* __restrict__ part) {
  __shared__ int lcnt[NB];
  __shared__ int lpos[NB];
  const int t = threadIdx.x;
  for (int i = t; i < NB; i += PART_THREADS) lcnt[i] = 0;
  __syncthreads();
  const int beg = blockIdx.x * PART_CHUNK;
  const int end = min(beg + PART_CHUNK, N_EDGES);
  for (int i = beg + t; i < end; i += PART_THREADS)
    atomicAdd(&lcnt[edst[i] >> BSHIFT], 1);
  __syncthreads();
  for (int i = t; i < NB; i += PART_THREADS)
    lpos[i] = lcnt[i] ? atomicAdd(&gcur[i], lcnt[i]) : 0;
  __syncthreads();
  for (int i = beg + t; i < end; i += PART_THREADS) {
    const int d = edst[i];
    const int p = atomicAdd(&lpos[d >> BSHIFT], 1);
    part[p] = make_int2((esrc[i] << BSHIFT) | (d & 63), __float_as_int(ew[i]));
  }
}

// ---------------------------------------------------------------------------
// Kernel 5: per-bucket LDS counting sort + register-accumulate + finalize.
// One 512-thread block per 64-node bucket. Per <=2048-edge chunk:
//   stage (coalesced) -> 64-bin count (int LDS atomics) -> 1-wave shfl scan
//   -> LDS scatter to dst-sorted order -> wave w accumulates nodes
//   [w*8, w*8+8) from sorted segments into 8 VGPR accumulators.
// No float atomics anywhere. Epilogue: bias + LN(64) + ReLU + resid.
// ---------------------------------------------------------------------------
__global__ __launch_bounds__(512, 4) void bucket_sort_accum(
    const unsigned short* __restrict__ support, const int2* __restrict__ part,
    const int* __restrict__ bstart, const float* __restrict__ resid,
    const float* __restrict__ bias, const float* __restrict__ gamma,
    const float* __restrict__ beta, float* __restrict__ out) {
  __shared__ int2 stage[CH];    // 16 KB
  __shared__ int2 sorted[CH];   // 16 KB
  __shared__ int bcnt2[BNODES];
  __shared__ int bseg[BNODES];
  __shared__ int bpos[BNODES];
  const int tid = threadIdx.x;
  const int o = tid & 63;
  const int wid = tid >> 6;  // 0..7
  const int b = blockIdx.x;
  const int beg = bstart[b];
  const int end = bstart[b + 1];

  float acc8[8];
#pragma unroll
  for (int t = 0; t < 8; ++t) acc8[t] = 0.f;

  for (int base = beg; base < end; base += CH) {
    const int n = min(CH, end - base);
    __syncthreads();  // previous chunk fully consumed
    if (tid < BNODES) bcnt2[tid] = 0;
    __syncthreads();

    // stage + bin count
    for (int i = tid; i < n; i += 512) {
      const int2 r = part[base + i];
      stage[i] = r;
      atomicAdd(&bcnt2[r.x & 63], 1);
    }
    __syncthreads();

    // exclusive scan of 64 bins (wave 0)
    if (wid == 0) {
      const int v = bcnt2[o];
      int incl = v;
#pragma unroll
      for (int off = 1; off < 64; off <<= 1) {
        const int u = __shfl_up(incl, off, 64);
        if (o >= off) incl += u;
      }
      bseg[o] = incl - v;
      bpos[o] = incl - v;
    }
    __syncthreads();

    // scatter to dst-sorted order (LDS -> LDS)
    for (int i = tid; i < n; i += 512) {
      const int2 r = stage[i];
      const int p = atomicAdd(&bpos[r.x & 63], 1);
      sorted[p] = r;
    }
    __syncthreads();

    // consume: wave wid owns nodes wid*8 .. wid*8+7
#pragma unroll
    for (int t = 0; t < 8; ++t) {
      const int j = wid * 8 + t;
      const int s = bseg[j];
      const int c = bcnt2[j];
      float a = acc8[t];
      int e = 0;
      for (; e + 4 <= c; e += 4) {
        const int2 m0 = sorted[s + e + 0];
        const int2 m1 = sorted[s + e + 1];
        const int2 m2 = sorted[s + e + 2];
        const int2 m3 = sorted[s + e + 3];
        const float v0 = bf2f(support[((size_t)((unsigned)m0.x >> 6) << 6) + o]);
        const float v1 = bf2f(support[((size_t)((unsigned)m1.x >> 6) << 6) + o]);
        const float v2 = bf2f(support[((size_t)((unsigned)m2.x >> 6) << 6) + o]);
        const float v3 = bf2f(support[((size_t)((unsigned)m3.x >> 6) << 6) + o]);
        a = fmaf(v0, __int_as_float(m0.y), a);
        a = fmaf(v1, __int_as_float(m1.y), a);
        a = fmaf(v2, __int_as_float(m2.y), a);
        a = fmaf(v3, __int_as_float(m3.y), a);
      }
      for (; e < c; ++e) {
        const int2 m = sorted[s + e];
        a = fmaf(bf2f(support[((size_t)((unsigned)m.x >> 6) << 6) + o]),
                 __int_as_float(m.y), a);
      }
      acc8[t] = a;
    }
  }

  // epilogue: bias + LN + ReLU + resid, one coalesced store per node
  const float bi = bias[o];
  const float ga = gamma[o];
  const float be = beta[o];
#pragma unroll
  for (int t = 0; t < 8; ++t) {
    const int j = wid * 8 + t;
    const int nid = (b << BSHIFT) + j;
    if (nid < N_NODES) {
      const float v = acc8[t] + bi;
      float s = v, sq = v * v;
#pragma unroll
      for (int off = 32; off > 0; off >>= 1) {
        s += __shfl_xor(s, off, 64);
        sq += __shfl_xor(sq, off, 64);
      }
      const float mu = s * (1.f / 64.f);
      const float var = sq * (1.f / 64.f) - mu * mu;
      const float r = rsqrtf(var + LN_EPS);
      const float nrm = fmaxf((v - mu) * r * ga + be, 0.f);
      out[(size_t)nid * OUT_F + o] = nrm + resid[(size_t)nid * OUT_F + o];
    }
  }
}

// ---------------------------------------------------------------------------
extern "C" void kernel_launch(void* const* d_in, const int* in_sizes, int n_in,
                              void* d_out, int out_size, void* d_ws,
                              size_t ws_size, hipStream_t stream) {
  const float* x      = (const float*)d_in[0];
  const float* weight = (const float*)d_in[1];
  const float* bias   = (const float*)d_in[2];
  const float* gamma  = (const float*)d_in[3];
  const float* beta   = (const float*)d_in[4];
  const float* res_w  = (const float*)d_in[5];
  const float* res_b  = (const float*)d_in[6];
  const float* ew     = (const float*)d_in[7];
  const int*   esrc   = (const int*)d_in[8];
  const int*   edst   = (const int*)d_in[9];
  float* out = (float*)d_out;

  char* ws = (char*)d_ws;
  size_t off = 0;
  auto alloc = [&](size_t bytes) {
    void* p = ws + off;
    off += (bytes + 255) & ~(size_t)255;
    return p;
  };
  unsigned short* support = (unsigned short*)alloc((size_t)N_NODES * OUT_F * 2); // 12.8MB
  float* resid   = (float*)alloc((size_t)N_NODES * OUT_F * sizeof(float));       // 25.6MB
  int2*  part    = (int2*)alloc((size_t)N_EDGES * sizeof(int2));                 // 12.8MB
  int*   bcnt    = (int*)alloc((size_t)NB * sizeof(int));
  int*   gcur    = (int*)alloc((size_t)NB * sizeof(int));
  int*   bstart  = (int*)alloc((size_t)(NB + 1) * sizeof(int));

  hipMemsetAsync(bcnt, 0, (size_t)NB * sizeof(int), stream);

  dual_gemm<<<1024, 512, 0, stream>>>(x, weight, res_w, res_b, support, resid);
  bucket_hist<<<512, 256, 0, stream>>>(edst, bcnt);
  bucket_scan<<<1, 1024, 0, stream>>>(bcnt, gcur, bstart);
  partition<<<PART_BLOCKS, PART_THREADS, 0, stream>>>(esrc, edst, ew, gcur, part);
  bucket_sort_accum<<<NB, 512, 0, stream>>>(support, part, bstart, resid,
                                            bias, gamma, beta, out);
}

// Round 6
// 275.807 us; speedup vs baseline: 4.0029x; 1.3800x over previous
//
#include <hip/hip_runtime.h>

#define N_NODES 100000
#define N_EDGES 1600000
#define IN_F 128
#define OUT_F 64
#define LN_EPS 1e-5f

#define BSHIFT 6                              // 64 nodes per bucket
#define BNODES 64
#define NB ((N_NODES + BNODES - 1) >> BSHIFT) // 1563

#define PART_BLOCKS 64
#define PART_THREADS 1024
#define PART_CHUNK ((N_EDGES + PART_BLOCKS - 1) / PART_BLOCKS)  // 25000

#define CH 2048  // per-chunk sort capacity

// GEMM tiling
#define MT 64                                  // rows per block
#define NGEMM ((N_NODES + MT - 1) / MT)        // 1563 blocks
#define LDA 136                                // 128 + 8 bf16 pad (272 B)

typedef __attribute__((ext_vector_type(8))) short short8;
typedef __attribute__((ext_vector_type(4))) short short4v;
typedef __attribute__((ext_vector_type(4))) float f32x4;

__device__ __forceinline__ unsigned short f2bf(float f) {
  unsigned int u = __float_as_uint(f);
  unsigned int r = (u + 0x7FFFu + ((u >> 16) & 1u)) >> 16;
  return (unsigned short)r;
}
__device__ __forceinline__ float bf2f(unsigned short h) {
  return __uint_as_float((unsigned int)h << 16);
}

// ---------------------------------------------------------------------------
// Kernel 1: fused MFMA GEMM.  C[100000,128] = x[100000,128] @ Bcat[128,128]
//   Bcat[:, 0:64] = W,  Bcat[:, 64:128] = res_w.T
//   cols 0-63  -> support (bf16),  cols 64-127 -> resid = . + res_b (f32)
// One block (4 waves) per 64-row M-tile. B^T staged in LDS (k-contiguous,
// padded); A-tile converted f32->bf16 in-flight. 32 mfma_16x16x32_bf16/wave.
// Layouts (verified m89/m91/m118/m120): A[m=lane&15][k=quad*8+j];
// B[k=quad*8+j][n=lane&15] (so read B^T rows contiguous); C col=lane&15,
// row=quad*4+reg.
// ---------------------------------------------------------------------------
__global__ __launch_bounds__(256) void mfma_gemm(
    const float* __restrict__ x, const float* __restrict__ W,
    const float* __restrict__ res_w, const float* __restrict__ res_b,
    unsigned short* __restrict__ support, float* __restrict__ resid) {
  __shared__ __align__(16) short bt[128 * LDA];  // B^T [n][k] bf16, 34 KB
  __shared__ __align__(16) short al[MT * LDA];   // A   [m][k] bf16, 17 KB
  const int tid = threadIdx.x;

  // --- stage B^T ---
  // n < 64:  Bt[n][k] = W[k*64+n]      (coalesced read over W)
  for (int i = tid; i < 128 * 64; i += 256) {
    const int k = i >> 6, n = i & 63;
    bt[n * LDA + k] = (short)f2bf(W[i]);
  }
  // n >= 64: Bt[n][k] = res_w[(n-64)*128 + k]  (coalesced read over res_w)
  for (int i = tid; i < 64 * 128; i += 256) {
    const int np = i >> 7, k = i & 127;
    bt[(64 + np) * LDA + k] = (short)f2bf(res_w[i]);
  }

  // --- stage A-tile (64 rows x 128 cols), f32 -> bf16 ---
  const size_t row0 = (size_t)blockIdx.x * MT;
  for (int i = tid; i < MT * 32; i += 256) {  // 2048 float4s
    const int r = i >> 5, c4 = i & 31;
    const size_t grow = row0 + r;
    float4 v = make_float4(0.f, 0.f, 0.f, 0.f);
    if (grow < N_NODES) v = ((const float4*)x)[grow * 32 + c4];
    short4v p;
    p.x = (short)f2bf(v.x); p.y = (short)f2bf(v.y);
    p.z = (short)f2bf(v.z); p.w = (short)f2bf(v.w);
    *(short4v*)(&al[r * LDA + c4 * 4]) = p;  // 8B aligned (272r + 8c4)
  }
  __syncthreads();

  // --- MFMA compute ---
  const int w = tid >> 6;          // wave 0..3 -> rows [w*16, w*16+16)
  const int lane = tid & 63;
  const int m16 = lane & 15;
  const int quad = lane >> 4;      // 0..3

  short8 afr[4];
#pragma unroll
  for (int kt = 0; kt < 4; ++kt)
    afr[kt] = *(const short8*)(&al[(w * 16 + m16) * LDA + kt * 32 + quad * 8]);

#pragma unroll
  for (int nt = 0; nt < 8; ++nt) {
    f32x4 acc = {0.f, 0.f, 0.f, 0.f};
#pragma unroll
    for (int kt = 0; kt < 4; ++kt) {
      const short8 bfr =
          *(const short8*)(&bt[(nt * 16 + m16) * LDA + kt * 32 + quad * 8]);
      acc = __builtin_amdgcn_mfma_f32_16x16x32_bf16(afr[kt], bfr, acc, 0, 0, 0);
    }
    const int col = nt * 16 + m16;
    const float rb = (col >= 64) ? res_b[col - 64] : 0.f;
#pragma unroll
    for (int r = 0; r < 4; ++r) {
      const size_t row = row0 + w * 16 + quad * 4 + r;
      if (row < N_NODES) {
        if (col < 64) support[row * OUT_F + col] = f2bf(acc[r]);
        else          resid[row * OUT_F + (col - 64)] = acc[r] + rb;
      }
    }
  }
}

// ---------------------------------------------------------------------------
// Kernel 2: bucket histogram (unchanged).
// ---------------------------------------------------------------------------
__global__ __launch_bounds__(256) void bucket_hist(const int* __restrict__ edst,
                                                   int* __restrict__ bcnt) {
  __shared__ int lc[NB];
  for (int i = threadIdx.x; i < NB; i += 256) lc[i] = 0;
  __syncthreads();
  const int stride = gridDim.x * 256;
  for (int i = blockIdx.x * 256 + threadIdx.x; i < N_EDGES; i += stride)
    atomicAdd(&lc[edst[i] >> BSHIFT], 1);
  __syncthreads();
  for (int i = threadIdx.x; i < NB; i += 256)
    if (lc[i]) atomicAdd(&bcnt[i], lc[i]);
}

// ---------------------------------------------------------------------------
// Kernel 3: exclusive scan over NB=1563 bucket counts (unchanged).
// ---------------------------------------------------------------------------
__global__ __launch_bounds__(1024) void bucket_scan(
    const int* __restrict__ bcnt, int* __restrict__ gcur,
    int* __restrict__ bstart) {
  __shared__ int sh[1024];
  __shared__ int tot;
  const int t = threadIdx.x;

  int v = bcnt[t];
  sh[t] = v;
  __syncthreads();
  for (int off = 1; off < 1024; off <<= 1) {
    int u = (t >= off) ? sh[t - off] : 0;
    __syncthreads();
    sh[t] += u;
    __syncthreads();
  }
  const int e1 = sh[t] - v;
  gcur[t] = e1;
  bstart[t] = e1;
  if (t == 1023) tot = sh[1023];
  __syncthreads();

  const int t2 = 1024 + t;
  int v2 = (t2 < NB) ? bcnt[t2] : 0;
  sh[t] = v2;
  __syncthreads();
  for (int off = 1; off < 1024; off <<= 1) {
    int u = (t >= off) ? sh[t - off] : 0;
    __syncthreads();
    sh[t] += u;
    __syncthreads();
  }
  if (t2 < NB) {
    const int e2 = sh[t] - v2 + tot;
    gcur[t2] = e2;
    bstart[t2] = e2;
  }
  if (t == 0) bstart[NB] = N_EDGES;
}

// ---------------------------------------------------------------------------
// Kernel 4: block-aggregated partition (unchanged).
// ---------------------------------------------------------------------------
__global__ __launch_bounds__(PART_THREADS) void partition(
    const int* __restrict__ esrc, const int* __restrict__ edst,
    const float* __restrict__ ew, int* __restrict__ gcur,
    int2* __restrict__ part) {
  __shared__ int lcnt[NB];
  __shared__ int lpos[NB];
  const int t = threadIdx.x;
  for (int i = t; i < NB; i += PART_THREADS) lcnt[i] = 0;
  __syncthreads();
  const int beg = blockIdx.x * PART_CHUNK;
  const int end = min(beg + PART_CHUNK, N_EDGES);
  for (int i = beg + t; i < end; i += PART_THREADS)
    atomicAdd(&lcnt[edst[i] >> BSHIFT], 1);
  __syncthreads();
  for (int i = t; i < NB; i += PART_THREADS)
    lpos[i] = lcnt[i] ? atomicAdd(&gcur[i], lcnt[i]) : 0;
  __syncthreads();
  for (int i = beg + t; i < end; i += PART_THREADS) {
    const int d = edst[i];
    const int p = atomicAdd(&lpos[d >> BSHIFT], 1);
    part[p] = make_int2((esrc[i] << BSHIFT) | (d & 63), __float_as_int(ew[i]));
  }
}

// ---------------------------------------------------------------------------
// Kernel 5: per-bucket LDS counting sort + register accumulate + finalize
// (unchanged from R5 — the 380 µs win).
// ---------------------------------------------------------------------------
__global__ __launch_bounds__(512, 4) void bucket_sort_accum(
    const unsigned short* __restrict__ support, const int2* __restrict__ part,
    const int* __restrict__ bstart, const float* __restrict__ resid,
    const float* __restrict__ bias, const float* __restrict__ gamma,
    const float* __restrict__ beta, float* __restrict__ out) {
  __shared__ int2 stage[CH];
  __shared__ int2 sorted[CH];
  __shared__ int bcnt2[BNODES];
  __shared__ int bseg[BNODES];
  __shared__ int bpos[BNODES];
  const int tid = threadIdx.x;
  const int o = tid & 63;
  const int wid = tid >> 6;
  const int b = blockIdx.x;
  const int beg = bstart[b];
  const int end = bstart[b + 1];

  float acc8[8];
#pragma unroll
  for (int t = 0; t < 8; ++t) acc8[t] = 0.f;

  for (int base = beg; base < end; base += CH) {
    const int n = min(CH, end - base);
    __syncthreads();
    if (tid < BNODES) bcnt2[tid] = 0;
    __syncthreads();

    for (int i = tid; i < n; i += 512) {
      const int2 r = part[base + i];
      stage[i] = r;
      atomicAdd(&bcnt2[r.x & 63], 1);
    }
    __syncthreads();

    if (wid == 0) {
      const int v = bcnt2[o];
      int incl = v;
#pragma unroll
      for (int off = 1; off < 64; off <<= 1) {
        const int u = __shfl_up(incl, off, 64);
        if (o >= off) incl += u;
      }
      bseg[o] = incl - v;
      bpos[o] = incl - v;
    }
    __syncthreads();

    for (int i = tid; i < n; i += 512) {
      const int2 r = stage[i];
      const int p = atomicAdd(&bpos[r.x & 63], 1);
      sorted[p] = r;
    }
    __syncthreads();

#pragma unroll
    for (int t = 0; t < 8; ++t) {
      const int j = wid * 8 + t;
      const int s = bseg[j];
      const int c = bcnt2[j];
      float a = acc8[t];
      int e = 0;
      for (; e + 4 <= c; e += 4) {
        const int2 m0 = sorted[s + e + 0];
        const int2 m1 = sorted[s + e + 1];
        const int2 m2 = sorted[s + e + 2];
        const int2 m3 = sorted[s + e + 3];
        const float v0 = bf2f(support[((size_t)((unsigned)m0.x >> 6) << 6) + o]);
        const float v1 = bf2f(support[((size_t)((unsigned)m1.x >> 6) << 6) + o]);
        const float v2 = bf2f(support[((size_t)((unsigned)m2.x >> 6) << 6) + o]);
        const float v3 = bf2f(support[((size_t)((unsigned)m3.x >> 6) << 6) + o]);
        a = fmaf(v0, __int_as_float(m0.y), a);
        a = fmaf(v1, __int_as_float(m1.y), a);
        a = fmaf(v2, __int_as_float(m2.y), a);
        a = fmaf(v3, __int_as_float(m3.y), a);
      }
      for (; e < c; ++e) {
        const int2 m = sorted[s + e];
        a = fmaf(bf2f(support[((size_t)((unsigned)m.x >> 6) << 6) + o]),
                 __int_as_float(m.y), a);
      }
      acc8[t] = a;
    }
  }

  const float bi = bias[o];
  const float ga = gamma[o];
  const float be = beta[o];
#pragma unroll
  for (int t = 0; t < 8; ++t) {
    const int j = wid * 8 + t;
    const int nid = (b << BSHIFT) + j;
    if (nid < N_NODES) {
      const float v = acc8[t] + bi;
      float s = v, sq = v * v;
#pragma unroll
      for (int off = 32; off > 0; off >>= 1) {
        s += __shfl_xor(s, off, 64);
        sq += __shfl_xor(sq, off, 64);
      }
      const float mu = s * (1.f / 64.f);
      const float var = sq * (1.f / 64.f) - mu * mu;
      const float r = rsqrtf(var + LN_EPS);
      const float nrm = fmaxf((v - mu) * r * ga + be, 0.f);
      out[(size_t)nid * OUT_F + o] = nrm + resid[(size_t)nid * OUT_F + o];
    }
  }
}

// ---------------------------------------------------------------------------
extern "C" void kernel_launch(void* const* d_in, const int* in_sizes, int n_in,
                              void* d_out, int out_size, void* d_ws,
                              size_t ws_size, hipStream_t stream) {
  const float* x      = (const float*)d_in[0];
  const float* weight = (const float*)d_in[1];
  const float* bias   = (const float*)d_in[2];
  const float* gamma  = (const float*)d_in[3];
  const float* beta   = (const float*)d_in[4];
  const float* res_w  = (const float*)d_in[5];
  const float* res_b  = (const float*)d_in[6];
  const float* ew     = (const float*)d_in[7];
  const int*   esrc   = (const int*)d_in[8];
  const int*   edst   = (const int*)d_in[9];
  float* out = (float*)d_out;

  char* ws = (char*)d_ws;
  size_t off = 0;
  auto alloc = [&](size_t bytes) {
    void* p = ws + off;
    off += (bytes + 255) & ~(size_t)255;
    return p;
  };
  unsigned short* support = (unsigned short*)alloc((size_t)N_NODES * OUT_F * 2); // 12.8MB
  float* resid   = (float*)alloc((size_t)N_NODES * OUT_F * sizeof(float));       // 25.6MB
  int2*  part    = (int2*)alloc((size_t)N_EDGES * sizeof(int2));                 // 12.8MB
  int*   bcnt    = (int*)alloc((size_t)NB * sizeof(int));
  int*   gcur    = (int*)alloc((size_t)NB * sizeof(int));
  int*   bstart  = (int*)alloc((size_t)(NB + 1) * sizeof(int));

  hipMemsetAsync(bcnt, 0, (size_t)NB * sizeof(int), stream);

  mfma_gemm<<<NGEMM, 256, 0, stream>>>(x, weight, res_w, res_b, support, resid);
  bucket_hist<<<512, 256, 0, stream>>>(edst, bcnt);
  bucket_scan<<<1, 1024, 0, stream>>>(bcnt, gcur, bstart);
  partition<<<PART_BLOCKS, PART_THREADS, 0, stream>>>(esrc, edst, ew, gcur, part);
  bucket_sort_accum<<<NB, 512, 0, stream>>>(support, part, bstart, resid,
                                            bias, gamma, beta, out);
}

// Round 7
// 245.072 us; speedup vs baseline: 4.5049x; 1.1254x over previous
//
#include <hip/hip_runtime.h>

#define N_NODES 100000
#define N_EDGES 1600000
#define IN_F 128
#define OUT_F 64
#define LN_EPS 1e-5f

#define BSHIFT 6                              // 64 nodes per bucket
#define BNODES 64
#define NB ((N_NODES + BNODES - 1) >> BSHIFT) // 1563

#define PART_BLOCKS 256
#define PART_THREADS 1024
#define PART_CHUNK ((N_EDGES + PART_BLOCKS - 1) / PART_BLOCKS)  // 6250

#define CH 2048  // per-chunk sort capacity

// GEMM tiling
#define MT 64                                  // rows per tile
#define NGEMM ((N_NODES + MT - 1) / MT)        // 1563 tiles
#define GEMM_BLOCKS 512                        // persistent blocks; B staged once
#define LDA 136                                // 128 + 8 bf16 pad (272 B)

typedef __attribute__((ext_vector_type(8))) short short8;
typedef __attribute__((ext_vector_type(4))) short short4v;
typedef __attribute__((ext_vector_type(4))) float f32x4;

__device__ __forceinline__ unsigned short f2bf(float f) {
  unsigned int u = __float_as_uint(f);
  unsigned int r = (u + 0x7FFFu + ((u >> 16) & 1u)) >> 16;
  return (unsigned short)r;
}
__device__ __forceinline__ float bf2f(unsigned short h) {
  return __uint_as_float((unsigned int)h << 16);
}

// ---------------------------------------------------------------------------
// Kernel 1: fused MFMA GEMM (persistent blocks).
//   C[100000,128] = x[100000,128] @ Bcat[128,128]
//   Bcat[:, 0:64] = W,  Bcat[:, 64:128] = res_w.T
//   cols 0-63 -> support (bf16), cols 64-127 -> resid = . + res_b (f32)
// B^T staged ONCE per block; grid-stride over 64-row M-tiles (~3 tiles/blk).
// ---------------------------------------------------------------------------
__global__ __launch_bounds__(256) void mfma_gemm(
    const float* __restrict__ x, const float* __restrict__ W,
    const float* __restrict__ res_w, const float* __restrict__ res_b,
    unsigned short* __restrict__ support, float* __restrict__ resid) {
  __shared__ __align__(16) short bt[128 * LDA];  // B^T [n][k] bf16, 34 KB
  __shared__ __align__(16) short al[MT * LDA];   // A   [m][k] bf16, 17 KB
  const int tid = threadIdx.x;

  // --- stage B^T once ---
  for (int i = tid; i < 128 * 64; i += 256) {          // W: [k,64] -> bt[n][k]
    const int k = i >> 6, n = i & 63;
    bt[n * LDA + k] = (short)f2bf(W[i]);
  }
  for (int i = tid; i < 64 * 128; i += 256) {          // res_w: [n',k] -> bt[64+n'][k]
    const int np = i >> 7, k = i & 127;
    bt[(64 + np) * LDA + k] = (short)f2bf(res_w[i]);
  }

  const int w = tid >> 6;          // wave 0..3 -> rows [w*16, w*16+16)
  const int lane = tid & 63;
  const int m16 = lane & 15;
  const int quad = lane >> 4;      // 0..3

  // hoist res_b per (nt): cols 64..127 live in nt 4..7
  float rbv[8];
#pragma unroll
  for (int nt = 0; nt < 8; ++nt)
    rbv[nt] = (nt >= 4) ? res_b[nt * 16 + m16 - 64] : 0.f;

  for (int g = blockIdx.x; g < NGEMM; g += GEMM_BLOCKS) {
    __syncthreads();  // al consumed by previous iter; bt staged (first iter)

    // --- stage A-tile (64 rows x 128 cols), f32 -> bf16 ---
    const size_t row0 = (size_t)g * MT;
    for (int i = tid; i < MT * 32; i += 256) {  // 2048 float4s
      const int r = i >> 5, c4 = i & 31;
      const size_t grow = row0 + r;
      float4 v = make_float4(0.f, 0.f, 0.f, 0.f);
      if (grow < N_NODES) v = ((const float4*)x)[grow * 32 + c4];
      short4v p;
      p.x = (short)f2bf(v.x); p.y = (short)f2bf(v.y);
      p.z = (short)f2bf(v.z); p.w = (short)f2bf(v.w);
      *(short4v*)(&al[r * LDA + c4 * 4]) = p;
    }
    __syncthreads();

    short8 afr[4];
#pragma unroll
    for (int kt = 0; kt < 4; ++kt)
      afr[kt] = *(const short8*)(&al[(w * 16 + m16) * LDA + kt * 32 + quad * 8]);

#pragma unroll
    for (int nt = 0; nt < 8; ++nt) {
      f32x4 acc = {0.f, 0.f, 0.f, 0.f};
#pragma unroll
      for (int kt = 0; kt < 4; ++kt) {
        const short8 bfr =
            *(const short8*)(&bt[(nt * 16 + m16) * LDA + kt * 32 + quad * 8]);
        acc = __builtin_amdgcn_mfma_f32_16x16x32_bf16(afr[kt], bfr, acc, 0, 0, 0);
      }
      const int col = nt * 16 + m16;
#pragma unroll
      for (int r = 0; r < 4; ++r) {
        const size_t row = row0 + w * 16 + quad * 4 + r;
        if (row < N_NODES) {
          if (col < 64) support[row * OUT_F + col] = f2bf(acc[r]);
          else          resid[row * OUT_F + (col - 64)] = acc[r] + rbv[nt];
        }
      }
    }
  }
}

// ---------------------------------------------------------------------------
// Kernel 2: bucket histogram (unchanged).
// ---------------------------------------------------------------------------
__global__ __launch_bounds__(256) void bucket_hist(const int* __restrict__ edst,
                                                   int* __restrict__ bcnt) {
  __shared__ int lc[NB];
  for (int i = threadIdx.x; i < NB; i += 256) lc[i] = 0;
  __syncthreads();
  const int stride = gridDim.x * 256;
  for (int i = blockIdx.x * 256 + threadIdx.x; i < N_EDGES; i += stride)
    atomicAdd(&lc[edst[i] >> BSHIFT], 1);
  __syncthreads();
  for (int i = threadIdx.x; i < NB; i += 256)
    if (lc[i]) atomicAdd(&bcnt[i], lc[i]);
}

// ---------------------------------------------------------------------------
// Kernel 3: exclusive scan over NB=1563 bucket counts (unchanged).
// ---------------------------------------------------------------------------
__global__ __launch_bounds__(1024) void bucket_scan(
    const int* __restrict__ bcnt, int* __restrict__ gcur,
    int* __restrict__ bstart) {
  __shared__ int sh[1024];
  __shared__ int tot;
  const int t = threadIdx.x;

  int v = bcnt[t];
  sh[t] = v;
  __syncthreads();
  for (int off = 1; off < 1024; off <<= 1) {
    int u = (t >= off) ? sh[t - off] : 0;
    __syncthreads();
    sh[t] += u;
    __syncthreads();
  }
  const int e1 = sh[t] - v;
  gcur[t] = e1;
  bstart[t] = e1;
  if (t == 1023) tot = sh[1023];
  __syncthreads();

  const int t2 = 1024 + t;
  int v2 = (t2 < NB) ? bcnt[t2] : 0;
  sh[t] = v2;
  __syncthreads();
  for (int off = 1; off < 1024; off <<= 1) {
    int u = (t >= off) ? sh[t - off] : 0;
    __syncthreads();
    sh[t] += u;
    __syncthreads();
  }
  if (t2 < NB) {
    const int e2 = sh[t] - v2 + tot;
    gcur[t2] = e2;
    bstart[t2] = e2;
  }
  if (t == 0) bstart[NB] = N_EDGES;
}

// ---------------------------------------------------------------------------
// Kernel 4: block-aggregated partition. 256 blocks (one per CU) — R6's 64
// left 3/4 of the GPU idle (Occupancy 9.5%). Runs shrink 16->4 records;
// write amplification accepted (+~10 MB vs 50 µs latency win).
// ---------------------------------------------------------------------------
__global__ __launch_bounds__(PART_THREADS) void partition(
    const int* __restrict__ esrc, const int* __restrict__ edst,
    const float* __restrict__ ew, int* __restrict__ gcur,
    int2* __restrict__ part) {
  __shared__ int lcnt[NB];
  __shared__ int lpos[NB];
  const int t = threadIdx.x;
  for (int i = t; i < NB; i += PART_THREADS) lcnt[i] = 0;
  __syncthreads();
  const int beg = blockIdx.x * PART_CHUNK;
  const int end = min(beg + PART_CHUNK, N_EDGES);
  for (int i = beg + t; i < end; i += PART_THREADS)
    atomicAdd(&lcnt[edst[i] >> BSHIFT], 1);
  __syncthreads();
  for (int i = t; i < NB; i += PART_THREADS)
    lpos[i] = lcnt[i] ? atomicAdd(&gcur[i], lcnt[i]) : 0;
  __syncthreads();
  for (int i = beg + t; i < end; i += PART_THREADS) {
    const int d = edst[i];
    const int p = atomicAdd(&lpos[d >> BSHIFT], 1);
    part[p] = make_int2((esrc[i] << BSHIFT) | (d & 63), __float_as_int(ew[i]));
  }
}

// ---------------------------------------------------------------------------
// Kernel 5: per-bucket LDS counting sort + register accumulate + finalize
// (unchanged — the R5 win).
// ---------------------------------------------------------------------------
__global__ __launch_bounds__(512, 4) void bucket_sort_accum(
    const unsigned short* __restrict__ support, const int2* __restrict__ part,
    const int* __restrict__ bstart, const float* __restrict__ resid,
    const float* __restrict__ bias, const float* __restrict__ gamma,
    const float* __restrict__ beta, float* __restrict__ out) {
  __shared__ int2 stage[CH];
  __shared__ int2 sorted[CH];
  __shared__ int bcnt2[BNODES];
  __shared__ int bseg[BNODES];
  __shared__ int bpos[BNODES];
  const int tid = threadIdx.x;
  const int o = tid & 63;
  const int wid = tid >> 6;
  const int b = blockIdx.x;
  const int beg = bstart[b];
  const int end = bstart[b + 1];

  float acc8[8];
#pragma unroll
  for (int t = 0; t < 8; ++t) acc8[t] = 0.f;

  for (int base = beg; base < end; base += CH) {
    const int n = min(CH, end - base);
    __syncthreads();
    if (tid < BNODES) bcnt2[tid] = 0;
    __syncthreads();

    for (int i = tid; i < n; i += 512) {
      const int2 r = part[base + i];
      stage[i] = r;
      atomicAdd(&bcnt2[r.x & 63], 1);
    }
    __syncthreads();

    if (wid == 0) {
      const int v = bcnt2[o];
      int incl = v;
#pragma unroll
      for (int off = 1; off < 64; off <<= 1) {
        const int u = __shfl_up(incl, off, 64);
        if (o >= off) incl += u;
      }
      bseg[o] = incl - v;
      bpos[o] = incl - v;
    }
    __syncthreads();

    for (int i = tid; i < n; i += 512) {
      const int2 r = stage[i];
      const int p = atomicAdd(&bpos[r.x & 63], 1);
      sorted[p] = r;
    }
    __syncthreads();

#pragma unroll
    for (int t = 0; t < 8; ++t) {
      const int j = wid * 8 + t;
      const int s = bseg[j];
      const int c = bcnt2[j];
      float a = acc8[t];
      int e = 0;
      for (; e + 4 <= c; e += 4) {
        const int2 m0 = sorted[s + e + 0];
        const int2 m1 = sorted[s + e + 1];
        const int2 m2 = sorted[s + e + 2];
        const int2 m3 = sorted[s + e + 3];
        const float v0 = bf2f(support[((size_t)((unsigned)m0.x >> 6) << 6) + o]);
        const float v1 = bf2f(support[((size_t)((unsigned)m1.x >> 6) << 6) + o]);
        const float v2 = bf2f(support[((size_t)((unsigned)m2.x >> 6) << 6) + o]);
        const float v3 = bf2f(support[((size_t)((unsigned)m3.x >> 6) << 6) + o]);
        a = fmaf(v0, __int_as_float(m0.y), a);
        a = fmaf(v1, __int_as_float(m1.y), a);
        a = fmaf(v2, __int_as_float(m2.y), a);
        a = fmaf(v3, __int_as_float(m3.y), a);
      }
      for (; e < c; ++e) {
        const int2 m = sorted[s + e];
        a = fmaf(bf2f(support[((size_t)((unsigned)m.x >> 6) << 6) + o]),
                 __int_as_float(m.y), a);
      }
      acc8[t] = a;
    }
  }

  const float bi = bias[o];
  const float ga = gamma[o];
  const float be = beta[o];
#pragma unroll
  for (int t = 0; t < 8; ++t) {
    const int j = wid * 8 + t;
    const int nid = (b << BSHIFT) + j;
    if (nid < N_NODES) {
      const float v = acc8[t] + bi;
      float s = v, sq = v * v;
#pragma unroll
      for (int off = 32; off > 0; off >>= 1) {
        s += __shfl_xor(s, off, 64);
        sq += __shfl_xor(sq, off, 64);
      }
      const float mu = s * (1.f / 64.f);
      const float var = sq * (1.f / 64.f) - mu * mu;
      const float r = rsqrtf(var + LN_EPS);
      const float nrm = fmaxf((v - mu) * r * ga + be, 0.f);
      out[(size_t)nid * OUT_F + o] = nrm + resid[(size_t)nid * OUT_F + o];
    }
  }
}

// ---------------------------------------------------------------------------
extern "C" void kernel_launch(void* const* d_in, const int* in_sizes, int n_in,
                              void* d_out, int out_size, void* d_ws,
                              size_t ws_size, hipStream_t stream) {
  const float* x      = (const float*)d_in[0];
  const float* weight = (const float*)d_in[1];
  const float* bias   = (const float*)d_in[2];
  const float* gamma  = (const float*)d_in[3];
  const float* beta   = (const float*)d_in[4];
  const float* res_w  = (const float*)d_in[5];
  const float* res_b  = (const float*)d_in[6];
  const float* ew     = (const float*)d_in[7];
  const int*   esrc   = (const int*)d_in[8];
  const int*   edst   = (const int*)d_in[9];
  float* out = (float*)d_out;

  char* ws = (char*)d_ws;
  size_t off = 0;
  auto alloc = [&](size_t bytes) {
    void* p = ws + off;
    off += (bytes + 255) & ~(size_t)255;
    return p;
  };
  unsigned short* support = (unsigned short*)alloc((size_t)N_NODES * OUT_F * 2); // 12.8MB
  float* resid   = (float*)alloc((size_t)N_NODES * OUT_F * sizeof(float));       // 25.6MB
  int2*  part    = (int2*)alloc((size_t)N_EDGES * sizeof(int2));                 // 12.8MB
  int*   bcnt    = (int*)alloc((size_t)NB * sizeof(int));
  int*   gcur    = (int*)alloc((size_t)NB * sizeof(int));
  int*   bstart  = (int*)alloc((size_t)(NB + 1) * sizeof(int));

  hipMemsetAsync(bcnt, 0, (size_t)NB * sizeof(int), stream);

  mfma_gemm<<<GEMM_BLOCKS, 256, 0, stream>>>(x, weight, res_w, res_b, support, resid);
  bucket_hist<<<512, 256, 0, stream>>>(edst, bcnt);
  bucket_scan<<<1, 1024, 0, stream>>>(bcnt, gcur, bstart);
  partition<<<PART_BLOCKS, PART_THREADS, 0, stream>>>(esrc, edst, ew, gcur, part);
  bucket_sort_accum<<<NB, 512, 0, stream>>>(support, part, bstart, resid,
                                            bias, gamma, beta, out);
}